// Round 13
// baseline (443.583 us; speedup 1.0000x reference)
//
#include <hip/hip_runtime.h>

// ---------------------------------------------------------------------------
// CausalLinearAttentionRSEEncoder — MFMA chunked attention + counted-vmcnt GEMMs
// B=4 T=2048 D=1024 H=16 K=64 BK=32 FFN=4096 LORA=48  NSUB=128 per (b,h)
// GEMMs: mfma_f32_32x32x16_bf16, counted-vmcnt double-buffer (LDS-BW-bound).
// ---------------------------------------------------------------------------

#define QS 3328

typedef __bf16 bf16x8 __attribute__((ext_vector_type(8)));
typedef float f32x4 __attribute__((ext_vector_type(4)));
typedef float f32x16 __attribute__((ext_vector_type(16)));

__device__ __forceinline__ unsigned short f2bf(float f) {
  unsigned int u = __builtin_bit_cast(unsigned int, f);
  u += 0x7FFFu + ((u >> 16) & 1u);
  return (unsigned short)(u >> 16);
}
__device__ __forceinline__ float bf2f(unsigned short u) {
  unsigned int x = ((unsigned int)u) << 16;
  return __builtin_bit_cast(float, x);
}
__device__ __forceinline__ unsigned int pack2(float a, float b) {
  return (unsigned int)f2bf(a) | ((unsigned int)f2bf(b) << 16);
}

__device__ __forceinline__ void gload_lds16(const void* g, void* l) {
  __builtin_amdgcn_global_load_lds((const __attribute__((address_space(1))) void*)g,
                                   (__attribute__((address_space(3))) void*)l, 16, 0, 0);
}

__device__ __forceinline__ float gelu_tanh(float v) {
  const float z = 0.7978845608028654f * fmaf(0.044715f * v * v, v, v);
  const float e = __expf(2.f * z);
  return 0.5f * v * (2.f - 2.f / (1.f + e));  // 0.5*v*(1+tanh(z))
}

// -------------------------------- fill (ws guard) ---------------------------
__global__ void fill_kernel(float* p, float v, int n) {
  int i = blockIdx.x * 256 + threadIdx.x;
  if (i < n) p[i] = v;
}

// -------------------------------- LayerNorm -> bf16 -------------------------
__global__ __launch_bounds__(256) void ln_kernel(
    const float* __restrict__ x, const float* __restrict__ g,
    const float* __restrict__ b, unsigned short* __restrict__ out) {
  const int row = blockIdx.x, tid = threadIdx.x;
  float4 v = ((const float4*)(x + (size_t)row * 1024))[tid];
  float s = v.x + v.y + v.z + v.w;
  float sq = v.x * v.x + v.y * v.y + v.z * v.z + v.w * v.w;
#pragma unroll
  for (int o = 32; o > 0; o >>= 1) { s += __shfl_xor(s, o); sq += __shfl_xor(sq, o); }
  __shared__ float red[8];
  const int wid = tid >> 6;
  if ((tid & 63) == 0) { red[wid] = s; red[4 + wid] = sq; }
  __syncthreads();
  s = red[0] + red[1] + red[2] + red[3];
  sq = red[4] + red[5] + red[6] + red[7];
  const float mean = s * (1.f / 1024.f);
  const float var = sq * (1.f / 1024.f) - mean * mean;
  const float rstd = rsqrtf(var + 1e-6f);
  float4 gv = ((const float4*)g)[tid];
  float4 bvv = ((const float4*)b)[tid];
  ushort4 o4;
  o4.x = f2bf((v.x - mean) * rstd * gv.x + bvv.x);
  o4.y = f2bf((v.y - mean) * rstd * gv.y + bvv.y);
  o4.z = f2bf((v.z - mean) * rstd * gv.z + bvv.z);
  o4.w = f2bf((v.w - mean) * rstd * gv.w + bvv.w);
  *(ushort4*)(out + (size_t)row * 1024 + tid * 4) = o4;
}

// ------------------------ unified weight prep (1 launch) --------------------
__device__ __forceinline__ void tr_tile(
    const float* __restrict__ src, unsigned short* __restrict__ dst,
    int K, int N, int bx, int by, int tx, int ty) {
  __shared__ float tile[32][33];
  const int n0 = bx * 32, k0 = by * 32;
#pragma unroll
  for (int j = 0; j < 32; j += 8) tile[tx][ty + j] = src[(size_t)(k0 + ty + j) * N + n0 + tx];
  __syncthreads();
#pragma unroll
  for (int j = 0; j < 32; j += 8)
    dst[(size_t)(n0 + ty + j) * K + k0 + tx] = f2bf(tile[ty + j][tx]);
}

__global__ __launch_bounds__(256) void prep_all(
    const float* __restrict__ Wq, const float* __restrict__ Wk,
    const float* __restrict__ Wv, const float* __restrict__ tw1,
    const float* __restrict__ Wo, const float* __restrict__ Wf1,
    const float* __restrict__ Wf2,
    const float* __restrict__ bq, const float* __restrict__ bk,
    const float* __restrict__ bv,
    unsigned short* __restrict__ WCAT, unsigned short* __restrict__ WOT,
    unsigned short* __restrict__ WF1T, unsigned short* __restrict__ WF2T,
    float* __restrict__ BIASC) {
  const int id = blockIdx.x;
  const int tx = threadIdx.x & 31, ty = threadIdx.x >> 5;
  if (id < 3328) {
    __shared__ float tile[32][33];
    const int bx = id % 104, by = id / 104;
    const int r0 = bx * 32, c0 = by * 32;
    const int r = r0 + tx;
#pragma unroll
    for (int j = 0; j < 32; j += 8) {
      const int c = c0 + ty + j;
      float v;
      if (r < 1024) v = Wq[(size_t)c * 1024 + r];
      else if (r < 2048) v = Wk[(size_t)c * 1024 + (r - 1024)];
      else if (r < 3072) v = Wv[(size_t)c * 1024 + (r - 2048)];
      else if (r < 3120) v = tw1[(size_t)c * 48 + (r - 3072)];
      else v = 0.f;
      tile[tx][ty + j] = v;
    }
    __syncthreads();
#pragma unroll
    for (int j = 0; j < 32; j += 8)
      WCAT[(size_t)(r0 + ty + j) * 1024 + c0 + tx] = f2bf(tile[ty + j][tx]);
  } else if (id < 4352) {
    const int i2 = id - 3328;
    tr_tile(Wo, WOT, 1024, 1024, i2 % 32, i2 / 32, tx, ty);
  } else if (id < 8448) {
    const int i3 = id - 4352;
    tr_tile(Wf1, WF1T, 1024, 4096, i3 % 128, i3 / 128, tx, ty);
  } else if (id < 12544) {
    const int i4 = id - 8448;
    tr_tile(Wf2, WF2T, 4096, 1024, i4 % 32, i4 / 32, tx, ty);
  } else {
    const int i5 = (id - 12544) * 256 + threadIdx.x;
    if (i5 < QS) {
      float v = 0.f;
      if (i5 < 1024) v = bq[i5];
      else if (i5 < 2048) v = bk[i5 - 1024];
      else if (i5 < 3072) v = bv[i5 - 2048];
      BIASC[i5] = v;
    }
  }
}

// ---------------- 256^2 counted-vmcnt GEMM (32x32x16 MFMA) ------------------
// 8 waves (2M x 4N); wave = 128M x 64N = 4 mrep x 2 nrep of 32x32.
// BK=64; 128KB LDS dbuf; counted vmcnt(4) never 0 mid-loop.
// MODE 2: bf16 gelu; MODE 3: bf16 plain.
template <int MODE>
__global__ __launch_bounds__(512, 2) void gemm8p_kernel(
    const unsigned short* __restrict__ A, const unsigned short* __restrict__ BT,
    const float* __restrict__ bias, void* __restrict__ out,
    int N, int Kstride, int Klen) {
  __shared__ __align__(16) unsigned short SA[2][2][8192];
  __shared__ __align__(16) unsigned short SB[2][2][8192];
  const int nwg = gridDim.x * gridDim.y;
  int d = blockIdx.y * gridDim.x + blockIdx.x;
  d = (d & 7) * (nwg >> 3) + (d >> 3);
  const int n0 = (d % gridDim.x) * 256, m0 = (d / gridDim.x) * 256;

  const int tid = threadIdx.x, wv = tid >> 6, ln = tid & 63;
  const int wm = wv >> 2, wn = wv & 3;
  const int l31 = ln & 31, hi5 = ln >> 5;

  const unsigned short* Abase = A + (size_t)m0 * Kstride;
  const unsigned short* Bbase = BT + (size_t)n0 * Kstride;

  const int srow = ln >> 3;
  const int skg = (ln & 7) ^ srow;
  const unsigned short* ga00 = Abase + (size_t)((0 * 8 + wv) * 8 + srow) * Kstride + skg * 8;
  const unsigned short* ga01 = Abase + (size_t)((1 * 8 + wv) * 8 + srow) * Kstride + skg * 8;
  const unsigned short* ga10 = Abase + (size_t)(128 + (0 * 8 + wv) * 8 + srow) * Kstride + skg * 8;
  const unsigned short* ga11 = Abase + (size_t)(128 + (1 * 8 + wv) * 8 + srow) * Kstride + skg * 8;
  const unsigned short* gb00 = Bbase + (size_t)((0 * 8 + wv) * 8 + srow) * Kstride + skg * 8;
  const unsigned short* gb01 = Bbase + (size_t)((1 * 8 + wv) * 8 + srow) * Kstride + skg * 8;
  const unsigned short* gb10 = Bbase + (size_t)(128 + (0 * 8 + wv) * 8 + srow) * Kstride + skg * 8;
  const unsigned short* gb11 = Bbase + (size_t)(128 + (1 * 8 + wv) * 8 + srow) * Kstride + skg * 8;

  auto STA = [&](int pbuf) {
    gload_lds16(ga00, (char*)SA + pbuf * 32768 + wv * 1024);
    gload_lds16(ga01, (char*)SA + pbuf * 32768 + (8 + wv) * 1024);
    gload_lds16(ga10, (char*)SA + pbuf * 32768 + 16384 + wv * 1024);
    gload_lds16(ga11, (char*)SA + pbuf * 32768 + 16384 + (8 + wv) * 1024);
    ga00 += 64; ga01 += 64; ga10 += 64; ga11 += 64;
  };
  auto STB = [&](int pbuf) {
    gload_lds16(gb00, (char*)SB + pbuf * 32768 + wv * 1024);
    gload_lds16(gb01, (char*)SB + pbuf * 32768 + (8 + wv) * 1024);
    gload_lds16(gb10, (char*)SB + pbuf * 32768 + 16384 + wv * 1024);
    gload_lds16(gb11, (char*)SB + pbuf * 32768 + 16384 + (8 + wv) * 1024);
    gb00 += 64; gb01 += 64; gb10 += 64; gb11 += 64;
  };

  const int x7 = l31 & 7;
  const char* aAk[4];
  const char* aBk[4];
#pragma unroll
  for (int ks = 0; ks < 4; ++ks) {
    const int ko = ((ks * 2 + hi5) ^ x7) * 16;
    aAk[ks] = (const char*)SA + wm * 16384 + l31 * 128 + ko;
    aBk[ks] = (const char*)SB + (wn >> 1) * 16384 + (wn & 1) * 8192 + l31 * 128 + ko;
  }

  f32x16 acc[4][2] = {};
  const int nt = Klen >> 6;   // even

  STA(0);
  STB(0);
  STA(1);
  asm volatile("s_waitcnt vmcnt(4)" ::: "memory");
  __builtin_amdgcn_s_barrier();

#define GTILE(P, T)                                                            \
  {                                                                            \
    if ((T) + 1 < nt) STB((P) ^ 1);                                            \
    _Pragma("unroll")                                                          \
    for (int ks = 0; ks < 4; ++ks) {                                           \
      bf16x8 b0 = *(const bf16x8*)(aBk[ks] + (P) * 32768);                     \
      bf16x8 b1 = *(const bf16x8*)(aBk[ks] + (P) * 32768 + 4096);              \
      bf16x8 a0 = *(const bf16x8*)(aAk[ks] + (P) * 32768);                     \
      bf16x8 a1 = *(const bf16x8*)(aAk[ks] + (P) * 32768 + 4096);              \
      bf16x8 a2 = *(const bf16x8*)(aAk[ks] + (P) * 32768 + 8192);              \
      bf16x8 a3 = *(const bf16x8*)(aAk[ks] + (P) * 32768 + 12288);             \
      __builtin_amdgcn_s_setprio(1);                                           \
      acc[0][0] = __builtin_amdgcn_mfma_f32_32x32x16_bf16(a0, b0, acc[0][0], 0, 0, 0); \
      acc[0][1] = __builtin_amdgcn_mfma_f32_32x32x16_bf16(a0, b1, acc[0][1], 0, 0, 0); \
      acc[1][0] = __builtin_amdgcn_mfma_f32_32x32x16_bf16(a1, b0, acc[1][0], 0, 0, 0); \
      acc[1][1] = __builtin_amdgcn_mfma_f32_32x32x16_bf16(a1, b1, acc[1][1], 0, 0, 0); \
      acc[2][0] = __builtin_amdgcn_mfma_f32_32x32x16_bf16(a2, b0, acc[2][0], 0, 0, 0); \
      acc[2][1] = __builtin_amdgcn_mfma_f32_32x32x16_bf16(a2, b1, acc[2][1], 0, 0, 0); \
      acc[3][0] = __builtin_amdgcn_mfma_f32_32x32x16_bf16(a3, b0, acc[3][0], 0, 0, 0); \
      acc[3][1] = __builtin_amdgcn_mfma_f32_32x32x16_bf16(a3, b1, acc[3][1], 0, 0, 0); \
      __builtin_amdgcn_s_setprio(0);                                           \
    }                                                                          \
    __builtin_amdgcn_s_barrier();                                              \
    if ((T) + 2 < nt) STA(P);                                                  \
    if ((T) + 1 < nt) {                                                        \
      if ((T) + 2 < nt) asm volatile("s_waitcnt vmcnt(4)" ::: "memory");       \
      else              asm volatile("s_waitcnt vmcnt(0)" ::: "memory");       \
      __builtin_amdgcn_s_barrier();                                            \
    }                                                                          \
  }

  for (int t = 0; t < nt; t += 2) {
    GTILE(0, t);
    GTILE(1, t + 1);
  }
#undef GTILE

#pragma unroll
  for (int mr = 0; mr < 4; ++mr) {
#pragma unroll
    for (int nr = 0; nr < 2; ++nr) {
      const int col = n0 + wn * 64 + nr * 32 + l31;
      const float bval = bias[col];
#pragma unroll
      for (int reg = 0; reg < 16; ++reg) {
        const int row = m0 + wm * 128 + mr * 32 + (reg & 3) + 8 * (reg >> 2) + 4 * hi5;
        const float v = acc[mr][nr][reg] + bval;
        const size_t oi = (size_t)row * N + col;
        if constexpr (MODE == 2) {
          ((unsigned short*)out)[oi] = f2bf(gelu_tanh(v));
        } else {
          ((unsigned short*)out)[oi] = f2bf(v);
        }
      }
    }
  }
}

// ---------------- 256x128 counted-vmcnt GEMM (32x32x16) ---------------------
// 8 waves (4M x 2N); wave = 64M x 64N = 2 mrep x 2 nrep of 32x32.
// MODE 1: fp32 out + res; MODE 3: bf16 plain out.
template <int MODE>
__global__ __launch_bounds__(512, 2) void gemm8pn_kernel(
    const unsigned short* __restrict__ A, const unsigned short* __restrict__ BT,
    const float* __restrict__ bias, const float* __restrict__ res,
    void* __restrict__ out, int N, int Kstride, int Klen) {
  __shared__ __align__(16) unsigned short SA[2][2][8192];  // 64KB
  __shared__ __align__(16) unsigned short SB[2][8192];     // 32KB
  const int nwg = gridDim.x * gridDim.y;
  int d = blockIdx.y * gridDim.x + blockIdx.x;
  d = (d & 7) * (nwg >> 3) + (d >> 3);
  const int n0 = (d % gridDim.x) * 128, m0 = (d / gridDim.x) * 256;

  const int tid = threadIdx.x, wv = tid >> 6, ln = tid & 63;
  const int wm = wv >> 1, wn = wv & 1;       // 4M x 2N
  const int l31 = ln & 31, hi5 = ln >> 5;

  const unsigned short* Abase = A + (size_t)m0 * Kstride;
  const unsigned short* Bbase = BT + (size_t)n0 * Kstride;

  const int srow = ln >> 3;
  const int skg = (ln & 7) ^ srow;
  const unsigned short* ga00 = Abase + (size_t)((0 * 8 + wv) * 8 + srow) * Kstride + skg * 8;
  const unsigned short* ga01 = Abase + (size_t)((1 * 8 + wv) * 8 + srow) * Kstride + skg * 8;
  const unsigned short* ga10 = Abase + (size_t)(128 + (0 * 8 + wv) * 8 + srow) * Kstride + skg * 8;
  const unsigned short* ga11 = Abase + (size_t)(128 + (1 * 8 + wv) * 8 + srow) * Kstride + skg * 8;
  const unsigned short* gb0 = Bbase + (size_t)((0 * 8 + wv) * 8 + srow) * Kstride + skg * 8;
  const unsigned short* gb1 = Bbase + (size_t)((1 * 8 + wv) * 8 + srow) * Kstride + skg * 8;

  auto STA = [&](int pbuf) {
    gload_lds16(ga00, (char*)SA + pbuf * 32768 + wv * 1024);
    gload_lds16(ga01, (char*)SA + pbuf * 32768 + (8 + wv) * 1024);
    gload_lds16(ga10, (char*)SA + pbuf * 32768 + 16384 + wv * 1024);
    gload_lds16(ga11, (char*)SA + pbuf * 32768 + 16384 + (8 + wv) * 1024);
    ga00 += 64; ga01 += 64; ga10 += 64; ga11 += 64;
  };
  auto STB = [&](int pbuf) {
    gload_lds16(gb0, (char*)SB + pbuf * 16384 + wv * 1024);
    gload_lds16(gb1, (char*)SB + pbuf * 16384 + (8 + wv) * 1024);
    gb0 += 64; gb1 += 64;
  };

  const int x7 = l31 & 7;
  const char* aAk[4];
  const char* aBk[4];
#pragma unroll
  for (int ks = 0; ks < 4; ++ks) {
    const int ko = ((ks * 2 + hi5) ^ x7) * 16;
    aAk[ks] = (const char*)SA + (wm >> 1) * 16384 + (wm & 1) * 8192 + l31 * 128 + ko;
    aBk[ks] = (const char*)SB + wn * 8192 + l31 * 128 + ko;
  }

  f32x16 acc[2][2] = {};
  const int nt = Klen >> 6;

  STA(0);
  STB(0);
  STA(1);
  asm volatile("s_waitcnt vmcnt(4)" ::: "memory");
  __builtin_amdgcn_s_barrier();

#define GTILEN(P, T)                                                           \
  {                                                                            \
    if ((T) + 1 < nt) STB((P) ^ 1);                                            \
    _Pragma("unroll")                                                          \
    for (int ks = 0; ks < 4; ++ks) {                                           \
      bf16x8 b0 = *(const bf16x8*)(aBk[ks] + (P) * 16384);                     \
      bf16x8 b1 = *(const bf16x8*)(aBk[ks] + (P) * 16384 + 4096);              \
      bf16x8 a0 = *(const bf16x8*)(aAk[ks] + (P) * 32768);                     \
      bf16x8 a1 = *(const bf16x8*)(aAk[ks] + (P) * 32768 + 4096);              \
      __builtin_amdgcn_s_setprio(1);                                           \
      acc[0][0] = __builtin_amdgcn_mfma_f32_32x32x16_bf16(a0, b0, acc[0][0], 0, 0, 0); \
      acc[0][1] = __builtin_amdgcn_mfma_f32_32x32x16_bf16(a0, b1, acc[0][1], 0, 0, 0); \
      acc[1][0] = __builtin_amdgcn_mfma_f32_32x32x16_bf16(a1, b0, acc[1][0], 0, 0, 0); \
      acc[1][1] = __builtin_amdgcn_mfma_f32_32x32x16_bf16(a1, b1, acc[1][1], 0, 0, 0); \
      __builtin_amdgcn_s_setprio(0);                                           \
    }                                                                          \
    __builtin_amdgcn_s_barrier();                                              \
    if ((T) + 2 < nt) STA(P);                                                  \
    if ((T) + 1 < nt) {                                                        \
      if ((T) + 2 < nt) asm volatile("s_waitcnt vmcnt(4)" ::: "memory");       \
      else              asm volatile("s_waitcnt vmcnt(0)" ::: "memory");       \
      __builtin_amdgcn_s_barrier();                                            \
    }                                                                          \
  }

  for (int t = 0; t < nt; t += 2) {
    GTILEN(0, t);
    GTILEN(1, t + 1);
  }
#undef GTILEN

#pragma unroll
  for (int mr = 0; mr < 2; ++mr) {
#pragma unroll
    for (int nr = 0; nr < 2; ++nr) {
      const int col = n0 + wn * 64 + nr * 32 + l31;
      const float bval = bias[col];
#pragma unroll
      for (int reg = 0; reg < 16; ++reg) {
        const int row = m0 + wm * 64 + mr * 32 + (reg & 3) + 8 * (reg >> 2) + 4 * hi5;
        const size_t oi = (size_t)row * N + col;
        const float v = acc[mr][nr][reg] + bval;
        if constexpr (MODE == 1) {
          ((float*)out)[oi] = v + res[oi];
        } else {
          ((unsigned short*)out)[oi] = f2bf(v);
        }
      }
    }
  }
}

// -------------------------- LoRA2 + theta (clip) ----------------------------
__global__ __launch_bounds__(256) void lora2_kernel(
    const unsigned short* __restrict__ qkv, const float* __restrict__ w2,
    const float* __restrict__ tbase, float* __restrict__ theta) {
  __shared__ float lt[8][48];
  const int m0 = blockIdx.x * 32;
  const int tid = threadIdx.x;
  const int col = tid * 2;
  const float tb0 = tbase[col], tb1 = tbase[col + 1];
  for (int grp = 0; grp < 4; ++grp) {
    const int mg = m0 + grp * 8;
    __syncthreads();
    for (int idx = tid; idx < 384; idx += 256) {
      const int tok = idx / 48, jj = idx % 48;
      lt[tok][jj] = tanhf(bf2f(qkv[(size_t)(mg + tok) * QS + 3072 + jj]));
    }
    __syncthreads();
    float a0[8], a1[8];
#pragma unroll
    for (int tok = 0; tok < 8; ++tok) { a0[tok] = tb0; a1[tok] = tb1; }
    for (int jj = 0; jj < 48; ++jj) {
      const float2 w = *(const float2*)&w2[(size_t)jj * 512 + col];
#pragma unroll
      for (int tok = 0; tok < 8; ++tok) {
        const float l = lt[tok][jj];
        a0[tok] = fmaf(l, w.x, a0[tok]);
        a1[tok] = fmaf(l, w.y, a1[tok]);
      }
    }
    const float CL = 1.5707963267948966f;
#pragma unroll
    for (int tok = 0; tok < 8; ++tok) {
      float c0 = fminf(fmaxf(a0[tok], -CL), CL);
      float c1 = fminf(fmaxf(a1[tok], -CL), CL);
      *(float2*)&theta[(size_t)(mg + tok) * 512 + col] = make_float2(c0, c1);
    }
  }
}

// ------------------------------- attn_intra ---------------------------------
__global__ __launch_bounds__(256) void attn_intra(
    const unsigned short* __restrict__ qkv, const float* __restrict__ theta,
    const float* __restrict__ lamb, const float* __restrict__ eta,
    unsigned short* __restrict__ yi, unsigned short* __restrict__ QG,
    unsigned short* __restrict__ TCG, float* __restrict__ Dg) {
  const int c = blockIdx.x, bh = blockIdx.y;
  const int b = bh >> 4, h = bh & 15;
  const int tid = threadIdx.x, wv = tid >> 6, lane = tid & 63;
  const int sc = c * 4 + wv;
  const int cid = bh * 128 + sc;
  const int mw = b * 2048 + sc * 16;

  __shared__ unsigned short QDm[4][16][64];
  __shared__ unsigned short KDm[4][16][64];
  __shared__ unsigned short KdET[4][64][32];
  __shared__ unsigned short VT[4][64][32];
  __shared__ unsigned short Gs[4][16][32];

  {
    unsigned int* kz = (unsigned int*)&KdET[wv][0][0];
    unsigned int* vz = (unsigned int*)&VT[wv][0][0];
    for (int idx = lane; idx < 512; idx += 64) {
      const int r = idx >> 3, p = (idx & 7) + 8;
      kz[r * 16 + p] = 0; vz[r * 16 + p] = 0;
    }
    unsigned int* gz = (unsigned int*)&Gs[wv][0][0];
    for (int idx = lane; idx < 128; idx += 64) {
      const int r = idx >> 3, p = (idx & 7) + 8;
      gz[r * 16 + p] = 0;
    }
  }
  for (int ss = 0; ss < 16; ++ss)
    VT[wv][lane][ss] = qkv[(size_t)(mw + ss) * QS + 2048 + h * 64 + lane];

  const int bk = lane & 31, th = lane >> 5;
  const float lb = lamb[h * 32 + bk], et = eta[h * 32 + bk];
  float L[8], Th[8], qr[8], qi[8], kr[8], ki[8];
  float runL = 0.f, runT = 0.f;
#pragma unroll
  for (int i = 0; i < 8; ++i) {
    const size_t m = (size_t)(mw + th * 8 + i);
    const float tv = theta[m * 512 + h * 32 + bk];
    const float lam = fmaf(et * tv, tv, lb);
    runL += lam; L[i] = runL;
    runT += tv;  Th[i] = runT;
    const unsigned int qp = *(const unsigned int*)&qkv[m * QS + h * 64 + 2 * bk];
    const unsigned int kp = *(const unsigned int*)&qkv[m * QS + 1024 + h * 64 + 2 * bk];
    qr[i] = bf2f((unsigned short)(qp & 0xFFFF)); qi[i] = bf2f((unsigned short)(qp >> 16));
    const float kx = bf2f((unsigned short)(kp & 0xFFFF));
    const float ky = bf2f((unsigned short)(kp >> 16));
    kr[i] = kx > 0.f ? kx + 1.f : __expf(kx);
    ki[i] = ky > 0.f ? ky + 1.f : __expf(ky);
  }
  const float oL = __shfl_xor(runL, 32), oT = __shfl_xor(runT, 32);
  const float Lm = th ? oL : runL;
  const float Tm = th ? oT : runT;
  const float Ltot = runL + oL, Ttot = runT + oT;
  const float Lbase = th ? oL : 0.f, Tbase = th ? oT : 0.f;
  float Es, Ec; __sincosf(Tm, &Es, &Ec);
  const float Ee = __expf(-Lm);
  const float Er = Ee * Ec, Ei = Ee * Es;
  float Fs, Fc; __sincosf(Ttot - Tm, &Fs, &Fc);
  const float Fe = __expf(-(Ltot - Lm));
  const float Fr = Fe * Fc, Fi = Fe * Fs;
  if (th == 0) {
    float Ds, Dc; __sincosf(Ttot, &Ds, &Dc);
    const float De = __expf(-Ltot);
    *(float2*)&Dg[((size_t)cid * 32 + bk) * 2] = make_float2(De * Dc, De * Ds);
  }
  unsigned int* qd32 = (unsigned int*)&QDm[wv][0][0];
  unsigned int* kd32 = (unsigned int*)&KDm[wv][0][0];
#pragma unroll
  for (int i = 0; i < 8; ++i) {
    const int t = th * 8 + i;
    const float Lg = Lbase + L[i], Tg = Tbase + Th[i];
    const float dm = __expf(-(Lg - Lm));
    float sn, cs; __sincosf(Tg - Tm, &sn, &cs);
    const float qmr = dm * (qr[i] * cs + qi[i] * sn);
    const float qmi = dm * (qr[i] * sn - qi[i] * cs);
    const float rd = 1.f / dm;
    const float kmr = rd * (kr[i] * cs + ki[i] * sn);
    const float kmi = rd * (ki[i] * cs - kr[i] * sn);
    const int sidx = (t * 32 + bk) ^ ((t & 7) << 2);
    qd32[sidx] = pack2(qmr, qmi);
    kd32[sidx] = pack2(kmr, -kmi);
    ((unsigned int*)QG)[(size_t)cid * 512 + t * 32 + bk] =
        pack2(qmr * Er - qmi * Ei, qmr * Ei + qmi * Er);
    const float er = kmr * Fr - kmi * Fi;
    const float ei = kmr * Fi + kmi * Fr;
    KdET[wv][bk][t] = f2bf(er);
    KdET[wv][32 + bk][t] = f2bf(ei);
  }

  const int l15 = lane & 15, hi = lane >> 4;
  const char* qb = (const char*)&QDm[wv][0][0];
  const char* kb = (const char*)&KDm[wv][0][0];
  f32x4 z = {};
  f32x4 g = z;
  {
    bf16x8 a0 = *(const bf16x8*)(qb + l15 * 128 + ((16 * hi) ^ ((l15 & 7) << 4)));
    bf16x8 b0 = *(const bf16x8*)(kb + l15 * 128 + ((16 * hi) ^ ((l15 & 7) << 4)));
    bf16x8 a1 = *(const bf16x8*)(qb + l15 * 128 + ((64 + 16 * hi) ^ ((l15 & 7) << 4)));
    bf16x8 b1 = *(const bf16x8*)(kb + l15 * 128 + ((64 + 16 * hi) ^ ((l15 & 7) << 4)));
    g = __builtin_amdgcn_mfma_f32_16x16x32_bf16(a0, b0, g, 0, 0, 0);
    g = __builtin_amdgcn_mfma_f32_16x16x32_bf16(a1, b1, g, 0, 0, 0);
  }
#pragma unroll
  for (int r = 0; r < 4; ++r) {
    const float gv = (l15 <= 4 * hi + r) ? g[r] : 0.f;
    Gs[wv][4 * hi + r][l15] = f2bf(gv);
  }
  const char* gsb = (const char*)&Gs[wv][0][0];
  const char* vtb = (const char*)&VT[wv][0][0];
  bf16x8 aG = *(const bf16x8*)(gsb + l15 * 64 + 16 * hi);
#pragma unroll
  for (int nt = 0; nt < 4; ++nt) {
    bf16x8 bV = *(const bf16x8*)(vtb + (nt * 16 + l15) * 64 + 16 * hi);
    f32x4 y = __builtin_amdgcn_mfma_f32_16x16x32_bf16(aG, bV, z, 0, 0, 0);
#pragma unroll
    for (int r = 0; r < 4; ++r)
      yi[(size_t)cid * 1024 + (4 * hi + r) * 64 + nt * 16 + l15] = f2bf(y[r]);
  }
  const char* keb = (const char*)&KdET[wv][0][0];
#pragma unroll
  for (int mt = 0; mt < 4; ++mt) {
    bf16x8 aT = *(const bf16x8*)(keb + (mt * 16 + l15) * 64 + 16 * hi);
#pragma unroll
    for (int nt = 0; nt < 4; ++nt) {
      bf16x8 bV = *(const bf16x8*)(vtb + (nt * 16 + l15) * 64 + 16 * hi);
      f32x4 t4 = __builtin_amdgcn_mfma_f32_16x16x32_bf16(aT, bV, z, 0, 0, 0);
#pragma unroll
      for (int r = 0; r < 4; ++r)
        TCG[(size_t)cid * 4096 + (mt * 16 + 4 * hi + r) * 64 + nt * 16 + l15] = f2bf(t4[r]);
    }
  }
}

// ------------------------------- scanB (coalesced) --------------------------
__global__ __launch_bounds__(256) void scanB_kernel(
    const unsigned short* __restrict__ TCG, const float* __restrict__ Dg,
    unsigned int* __restrict__ CPACK) {
  const int bh = blockIdx.x & 63, g = blockIdx.x >> 6;
  const int tid = threadIdx.x;
  const int v = tid & 63, bk = g * 4 + (tid >> 6);
  const size_t base = (size_t)bh * 128;
  float Cr = 0.f, Ci = 0.f;
  float trx[4], tix[4]; float2 dx[4];
  auto LOADQ = [&](int c0, float* tr, float* ti, float2* dd) {
#pragma unroll
    for (int u = 0; u < 4; ++u) {
      const size_t cid = base + c0 + u;
      tr[u] = bf2f(TCG[cid * 4096 + bk * 64 + v]);
      ti[u] = bf2f(TCG[cid * 4096 + (32 + bk) * 64 + v]);
      dd[u] = *(const float2*)&Dg[(cid * 32 + bk) * 2];
    }
  };
  LOADQ(0, trx, tix, dx);
  for (int c0 = 0; c0 < 128; c0 += 4) {
    float tra[4], tia[4]; float2 da[4];
#pragma unroll
    for (int u = 0; u < 4; ++u) { tra[u] = trx[u]; tia[u] = tix[u]; da[u] = dx[u]; }
    if (c0 + 4 < 128) LOADQ(c0 + 4, trx, tix, dx);
#pragma unroll
    for (int u = 0; u < 4; ++u) {
      CPACK[(base + c0 + u) * 2048 + bk * 64 + v] = pack2(Cr, -Ci);
      const float nr = fmaf(da[u].x, Cr, fmaf(-da[u].y, Ci, tra[u]));
      const float ni = fmaf(da[u].x, Ci, fmaf(da[u].y, Cr, tia[u]));
      Cr = nr; Ci = ni;
    }
  }
}

// ------------------------------- attn_cross ---------------------------------
__global__ __launch_bounds__(256) void attn_cross(
    const unsigned short* __restrict__ yi, const unsigned short* __restrict__ QG,
    const unsigned int* __restrict__ CPACK, unsigned short* __restrict__ attn) {
  const int c = blockIdx.x, bh = blockIdx.y;
  const int b = bh >> 4, h = bh & 15;
  const int tid = threadIdx.x, wv = tid >> 6, lane = tid & 63;
  const int sc = c * 4 + wv, cid = bh * 128 + sc;
  const int mw = b * 2048 + sc * 16;
  __shared__ unsigned short Cp[4][64][64];
  __shared__ unsigned short Qs[4][16][64];
  unsigned int* cp32 = (unsigned int*)&Cp[wv][0][0];
  const unsigned int* cg = CPACK + (size_t)cid * 2048;
  for (int bkq = 0; bkq < 32; ++bkq) {
    cp32[(lane * 32 + bkq) ^ ((lane & 7) << 2)] = cg[bkq * 64 + lane];
  }
  unsigned int* qs32 = (unsigned int*)&Qs[wv][0][0];
  const unsigned int* qg = (const unsigned int*)QG + (size_t)cid * 512;
  for (int ii = 0; ii < 8; ++ii) {
    const int flat = ii * 64 + lane;
    const int row = flat >> 5, col = flat & 31;
    qs32[(row * 32 + col) ^ ((row & 7) << 2)] = qg[flat];
  }
  const int l15 = lane & 15, hi = lane >> 4;
  const char* qb = (const char*)&Qs[wv][0][0];
  const char* cb = (const char*)&Cp[wv][0][0];
  bf16x8 a0 = *(const bf16x8*)(qb + l15 * 128 + ((16 * hi) ^ ((l15 & 7) << 4)));
  bf16x8 a1 = *(const bf16x8*)(qb + l15 * 128 + ((64 + 16 * hi) ^ ((l15 & 7) << 4)));
  f32x4 z = {};
#pragma unroll
  for (int nt = 0; nt < 4; ++nt) {
    const int vr = nt * 16 + l15;
    bf16x8 b0 = *(const bf16x8*)(cb + vr * 128 + ((16 * hi) ^ ((vr & 7) << 4)));
    bf16x8 b1 = *(const bf16x8*)(cb + vr * 128 + ((64 + 16 * hi) ^ ((vr & 7) << 4)));
    f32x4 y = __builtin_amdgcn_mfma_f32_16x16x32_bf16(a0, b0, z, 0, 0, 0);
    y = __builtin_amdgcn_mfma_f32_16x16x32_bf16(a1, b1, y, 0, 0, 0);
#pragma unroll
    for (int r = 0; r < 4; ++r) {
      const int t = 4 * hi + r;
      const float out = y[r] + bf2f(yi[(size_t)cid * 1024 + t * 64 + vr]);
      attn[(size_t)(mw + t) * 1024 + h * 64 + vr] = f2bf(out);
    }
  }
}

// ---------------------------------------------------------------------------
extern "C" void kernel_launch(void* const* d_in, const int* in_sizes, int n_in,
                              void* d_out, int out_size, void* d_ws, size_t ws_size,
                              hipStream_t stream) {
  const float* x   = (const float*)d_in[0];
  const float* Wq  = (const float*)d_in[1];
  const float* bq  = (const float*)d_in[2];
  const float* Wk  = (const float*)d_in[3];
  const float* bk_ = (const float*)d_in[4];
  const float* Wv  = (const float*)d_in[5];
  const float* bv  = (const float*)d_in[6];
  const float* Wo  = (const float*)d_in[7];
  const float* bo  = (const float*)d_in[8];
  const float* n1g = (const float*)d_in[9];
  const float* n1b = (const float*)d_in[10];
  const float* n2g = (const float*)d_in[11];
  const float* n2b = (const float*)d_in[12];
  const float* thb = (const float*)d_in[13];
  const float* tw1 = (const float*)d_in[14];
  const float* tw2 = (const float*)d_in[15];
  const float* lamb= (const float*)d_in[16];
  const float* eta = (const float*)d_in[17];
  const float* Wf1 = (const float*)d_in[18];
  const float* bf1 = (const float*)d_in[19];
  const float* Wf2 = (const float*)d_in[20];
  const float* bf2 = (const float*)d_in[21];

  char* ws = (char*)d_ws;
  size_t off = 0;
  auto alloc = [&](size_t bytes) {
    size_t r = off;
    off += (bytes + 255) & ~(size_t)255;
    return r;
  };
  unsigned short* WCAT = (unsigned short*)(ws + alloc((size_t)QS * 1024 * 2));
  unsigned short* WOT  = (unsigned short*)(ws + alloc(1024ull * 1024 * 2));
  unsigned short* WF1T = (unsigned short*)(ws + alloc(4096ull * 1024 * 2));
  unsigned short* WF2T = (unsigned short*)(ws + alloc(1024ull * 4096 * 2));
  float* BIASC = (float*)(ws + alloc((size_t)QS * 4));
  unsigned short* XN = (unsigned short*)(ws + alloc(8192ull * 1024 * 2));  // also LN2 out
  char* QKVbase = ws + alloc(8192ull * 4096 * 2);   // QKV bf16(QS) / CPACK / GBUF
  unsigned short* QKV = (unsigned short*)QKVbase;
  unsigned int* CPACK = (unsigned int*)QKVbase;     // after attn_intra
  unsigned short* GBUF = (unsigned short*)QKVbase;  // after attn_cross
  float* THETA = (float*)(ws + alloc(8192ull * 512 * 4));   // also ATTN bf16
  unsigned short* ATTN = (unsigned short*)THETA;
  char* YIbase = ws + alloc(8192ull * 1024 * 4);    // YI bf16 (16MB) / X1 fp32 (32MB)
  unsigned short* YI = (unsigned short*)YIbase;
  float* X1 = (float*)YIbase;
  unsigned short* QG = (unsigned short*)(ws + alloc(8192ull * 1024 * 2));
  unsigned short* TCG = (unsigned short*)(ws + alloc(8192ull * 4096 * 2)); // T (read-only after intra)
  float* DG = (float*)(ws + alloc(8192ull * 32 * 2 * 4));

  if (ws_size < off) {
    fill_kernel<<<dim3((out_size + 255) / 256), dim3(256), 0, stream>>>((float*)d_out, 12345.0f, out_size);
    return;
  }

  const dim3 b256(256), b512(512);

  // unified weight prep (1 launch)
  prep_all<<<dim3(12557), b256, 0, stream>>>(Wq, Wk, Wv, tw1, Wo, Wf1, Wf2,
                                             bq, bk_, bv, WCAT, WOT, WF1T, WF2T, BIASC);

  // LN1 -> xn (bf16)
  ln_kernel<<<dim3(8192), b256, 0, stream>>>(x, n1g, n1b, XN);
  // QKV + lora1 (bf16 out, stride QS, N-cover 3200 exactly) — 256x128
  gemm8pn_kernel<3><<<dim3(25, 32), b512, 0, stream>>>(XN, WCAT, BIASC, nullptr, QKV, QS, 1024, 1024);
  // lora2 -> theta
  lora2_kernel<<<dim3(256), b256, 0, stream>>>(QKV, tw2, thb, THETA);
  // attention
  attn_intra<<<dim3(32, 64), b256, 0, stream>>>(QKV, THETA, lamb, eta, YI, QG, TCG, DG);
  scanB_kernel<<<dim3(512), b256, 0, stream>>>(TCG, DG, CPACK);
  attn_cross<<<dim3(32, 64), b256, 0, stream>>>(YI, QG, CPACK, ATTN);
  // x1 = x + attn@Wo + bo — 256x128 (fp32 + res)
  gemm8pn_kernel<1><<<dim3(8, 32), b512, 0, stream>>>(ATTN, WOT, bo, x, X1, 1024, 1024, 1024);
  // LN2
  ln_kernel<<<dim3(8192), b256, 0, stream>>>(X1, n2g, n2b, XN);
  // FFN1 (gelu, bf16 out) — 256^2
  gemm8p_kernel<2><<<dim3(16, 32), b512, 0, stream>>>(XN, WF1T, bf1, GBUF, 4096, 1024, 1024);
  // FFN2 — 256x128, full K, fp32 + res -> d_out
  gemm8pn_kernel<1><<<dim3(8, 32), b512, 0, stream>>>(GBUF, WF2T, bf2, X1, (float*)d_out, 1024, 4096, 4096);
}

// Round 14
// 428.929 us; speedup vs baseline: 1.0342x; 1.0342x over previous
//
#include <hip/hip_runtime.h>

// ---------------------------------------------------------------------------
// CausalLinearAttentionRSEEncoder — MFMA chunked attention + counted-vmcnt GEMMs
// B=4 T=2048 D=1024 H=16 K=64 BK=32 FFN=4096 LORA=48  NSUB=128 per (b,h)
// GEMMs use mfma_f32_32x32x16_bf16 (C/D: col=lane&31, row=(reg&3)+8*(reg>>2)+4*(lane>>5))
// Best measured configuration of the session (431.1 µs) — final revert.
// ---------------------------------------------------------------------------

#define QS 3328

typedef __bf16 bf16x8 __attribute__((ext_vector_type(8)));
typedef float f32x4 __attribute__((ext_vector_type(4)));
typedef float f32x16 __attribute__((ext_vector_type(16)));

__device__ __forceinline__ unsigned short f2bf(float f) {
  unsigned int u = __builtin_bit_cast(unsigned int, f);
  u += 0x7FFFu + ((u >> 16) & 1u);
  return (unsigned short)(u >> 16);
}
__device__ __forceinline__ float bf2f(unsigned short u) {
  unsigned int x = ((unsigned int)u) << 16;
  return __builtin_bit_cast(float, x);
}
__device__ __forceinline__ unsigned int pack2(float a, float b) {
  return (unsigned int)f2bf(a) | ((unsigned int)f2bf(b) << 16);
}

__device__ __forceinline__ void gload_lds16(const void* g, void* l) {
  __builtin_amdgcn_global_load_lds((const __attribute__((address_space(1))) void*)g,
                                   (__attribute__((address_space(3))) void*)l, 16, 0, 0);
}

__device__ __forceinline__ float gelu_tanh(float v) {
  const float z = 0.7978845608028654f * fmaf(0.044715f * v * v, v, v);
  const float e = __expf(2.f * z);
  return 0.5f * v * (2.f - 2.f / (1.f + e));  // 0.5*v*(1+tanh(z))
}

// -------------------------------- fill (ws guard) ---------------------------
__global__ void fill_kernel(float* p, float v, int n) {
  int i = blockIdx.x * 256 + threadIdx.x;
  if (i < n) p[i] = v;
}

// -------------------------------- LayerNorm -> bf16 -------------------------
__global__ __launch_bounds__(256) void ln_kernel(
    const float* __restrict__ x, const float* __restrict__ g,
    const float* __restrict__ b, unsigned short* __restrict__ out) {
  const int row = blockIdx.x, tid = threadIdx.x;
  float4 v = ((const float4*)(x + (size_t)row * 1024))[tid];
  float s = v.x + v.y + v.z + v.w;
  float sq = v.x * v.x + v.y * v.y + v.z * v.z + v.w * v.w;
#pragma unroll
  for (int o = 32; o > 0; o >>= 1) { s += __shfl_xor(s, o); sq += __shfl_xor(sq, o); }
  __shared__ float red[8];
  const int wid = tid >> 6;
  if ((tid & 63) == 0) { red[wid] = s; red[4 + wid] = sq; }
  __syncthreads();
  s = red[0] + red[1] + red[2] + red[3];
  sq = red[4] + red[5] + red[6] + red[7];
  const float mean = s * (1.f / 1024.f);
  const float var = sq * (1.f / 1024.f) - mean * mean;
  const float rstd = rsqrtf(var + 1e-6f);
  float4 gv = ((const float4*)g)[tid];
  float4 bvv = ((const float4*)b)[tid];
  ushort4 o4;
  o4.x = f2bf((v.x - mean) * rstd * gv.x + bvv.x);
  o4.y = f2bf((v.y - mean) * rstd * gv.y + bvv.y);
  o4.z = f2bf((v.z - mean) * rstd * gv.z + bvv.z);
  o4.w = f2bf((v.w - mean) * rstd * gv.w + bvv.w);
  *(ushort4*)(out + (size_t)row * 1024 + tid * 4) = o4;
}

// ------------------------ unified weight prep (1 launch) --------------------
__device__ __forceinline__ void tr_tile(
    const float* __restrict__ src, unsigned short* __restrict__ dst,
    int K, int N, int bx, int by, int tx, int ty) {
  __shared__ float tile[32][33];
  const int n0 = bx * 32, k0 = by * 32;
#pragma unroll
  for (int j = 0; j < 32; j += 8) tile[tx][ty + j] = src[(size_t)(k0 + ty + j) * N + n0 + tx];
  __syncthreads();
#pragma unroll
  for (int j = 0; j < 32; j += 8)
    dst[(size_t)(n0 + ty + j) * K + k0 + tx] = f2bf(tile[ty + j][tx]);
}

__global__ __launch_bounds__(256) void prep_all(
    const float* __restrict__ Wq, const float* __restrict__ Wk,
    const float* __restrict__ Wv, const float* __restrict__ tw1,
    const float* __restrict__ Wo, const float* __restrict__ Wf1,
    const float* __restrict__ Wf2,
    const float* __restrict__ bq, const float* __restrict__ bk,
    const float* __restrict__ bv,
    unsigned short* __restrict__ WCAT, unsigned short* __restrict__ WOT,
    unsigned short* __restrict__ WF1T, unsigned short* __restrict__ WF2T,
    float* __restrict__ BIASC) {
  const int id = blockIdx.x;
  const int tx = threadIdx.x & 31, ty = threadIdx.x >> 5;
  if (id < 3328) {
    __shared__ float tile[32][33];
    const int bx = id % 104, by = id / 104;
    const int r0 = bx * 32, c0 = by * 32;
    const int r = r0 + tx;
#pragma unroll
    for (int j = 0; j < 32; j += 8) {
      const int c = c0 + ty + j;
      float v;
      if (r < 1024) v = Wq[(size_t)c * 1024 + r];
      else if (r < 2048) v = Wk[(size_t)c * 1024 + (r - 1024)];
      else if (r < 3072) v = Wv[(size_t)c * 1024 + (r - 2048)];
      else if (r < 3120) v = tw1[(size_t)c * 48 + (r - 3072)];
      else v = 0.f;
      tile[tx][ty + j] = v;
    }
    __syncthreads();
#pragma unroll
    for (int j = 0; j < 32; j += 8)
      WCAT[(size_t)(r0 + ty + j) * 1024 + c0 + tx] = f2bf(tile[ty + j][tx]);
  } else if (id < 4352) {
    const int i2 = id - 3328;
    tr_tile(Wo, WOT, 1024, 1024, i2 % 32, i2 / 32, tx, ty);
  } else if (id < 8448) {
    const int i3 = id - 4352;
    tr_tile(Wf1, WF1T, 1024, 4096, i3 % 128, i3 / 128, tx, ty);
  } else if (id < 12544) {
    const int i4 = id - 8448;
    tr_tile(Wf2, WF2T, 4096, 1024, i4 % 32, i4 / 32, tx, ty);
  } else {
    const int i5 = (id - 12544) * 256 + threadIdx.x;
    if (i5 < QS) {
      float v = 0.f;
      if (i5 < 1024) v = bq[i5];
      else if (i5 < 2048) v = bk[i5 - 1024];
      else if (i5 < 3072) v = bv[i5 - 2048];
      BIASC[i5] = v;
    }
  }
}

// ---------------- 256^2 counted-vmcnt GEMM (32x32x16 MFMA) ------------------
// 8 waves (2M x 4N); wave = 128M x 64N = 4 mrep x 2 nrep of 32x32.
// BK=64; 128KB LDS dbuf; counted vmcnt(4) never 0 mid-loop.
// MODE 2: bf16 gelu; MODE 3: bf16 plain.
template <int MODE>
__global__ __launch_bounds__(512, 2) void gemm8p_kernel(
    const unsigned short* __restrict__ A, const unsigned short* __restrict__ BT,
    const float* __restrict__ bias, void* __restrict__ out,
    int N, int Kstride, int Klen) {
  __shared__ __align__(16) unsigned short SA[2][2][8192];
  __shared__ __align__(16) unsigned short SB[2][2][8192];
  const int nwg = gridDim.x * gridDim.y;
  int d = blockIdx.y * gridDim.x + blockIdx.x;
  d = (d & 7) * (nwg >> 3) + (d >> 3);
  const int n0 = (d % gridDim.x) * 256, m0 = (d / gridDim.x) * 256;

  const int tid = threadIdx.x, wv = tid >> 6, ln = tid & 63;
  const int wm = wv >> 2, wn = wv & 3;
  const int l31 = ln & 31, hi5 = ln >> 5;

  const unsigned short* Abase = A + (size_t)m0 * Kstride;
  const unsigned short* Bbase = BT + (size_t)n0 * Kstride;

  const int srow = ln >> 3;
  const int skg = (ln & 7) ^ srow;
  const unsigned short* ga00 = Abase + (size_t)((0 * 8 + wv) * 8 + srow) * Kstride + skg * 8;
  const unsigned short* ga01 = Abase + (size_t)((1 * 8 + wv) * 8 + srow) * Kstride + skg * 8;
  const unsigned short* ga10 = Abase + (size_t)(128 + (0 * 8 + wv) * 8 + srow) * Kstride + skg * 8;
  const unsigned short* ga11 = Abase + (size_t)(128 + (1 * 8 + wv) * 8 + srow) * Kstride + skg * 8;
  const unsigned short* gb00 = Bbase + (size_t)((0 * 8 + wv) * 8 + srow) * Kstride + skg * 8;
  const unsigned short* gb01 = Bbase + (size_t)((1 * 8 + wv) * 8 + srow) * Kstride + skg * 8;
  const unsigned short* gb10 = Bbase + (size_t)(128 + (0 * 8 + wv) * 8 + srow) * Kstride + skg * 8;
  const unsigned short* gb11 = Bbase + (size_t)(128 + (1 * 8 + wv) * 8 + srow) * Kstride + skg * 8;

  auto STA = [&](int pbuf) {
    gload_lds16(ga00, (char*)SA + pbuf * 32768 + wv * 1024);
    gload_lds16(ga01, (char*)SA + pbuf * 32768 + (8 + wv) * 1024);
    gload_lds16(ga10, (char*)SA + pbuf * 32768 + 16384 + wv * 1024);
    gload_lds16(ga11, (char*)SA + pbuf * 32768 + 16384 + (8 + wv) * 1024);
    ga00 += 64; ga01 += 64; ga10 += 64; ga11 += 64;
  };
  auto STB = [&](int pbuf) {
    gload_lds16(gb00, (char*)SB + pbuf * 32768 + wv * 1024);
    gload_lds16(gb01, (char*)SB + pbuf * 32768 + (8 + wv) * 1024);
    gload_lds16(gb10, (char*)SB + pbuf * 32768 + 16384 + wv * 1024);
    gload_lds16(gb11, (char*)SB + pbuf * 32768 + 16384 + (8 + wv) * 1024);
    gb00 += 64; gb01 += 64; gb10 += 64; gb11 += 64;
  };

  const int x7 = l31 & 7;
  const char* aAk[4];
  const char* aBk[4];
#pragma unroll
  for (int ks = 0; ks < 4; ++ks) {
    const int ko = ((ks * 2 + hi5) ^ x7) * 16;
    aAk[ks] = (const char*)SA + wm * 16384 + l31 * 128 + ko;
    aBk[ks] = (const char*)SB + (wn >> 1) * 16384 + (wn & 1) * 8192 + l31 * 128 + ko;
  }

  f32x16 acc[4][2] = {};
  const int nt = Klen >> 6;   // even

  STA(0);
  STB(0);
  STA(1);
  asm volatile("s_waitcnt vmcnt(4)" ::: "memory");
  __builtin_amdgcn_s_barrier();

#define GTILE(P, T)                                                            \
  {                                                                            \
    if ((T) + 1 < nt) STB((P) ^ 1);                                            \
    _Pragma("unroll")                                                          \
    for (int ks = 0; ks < 4; ++ks) {                                           \
      bf16x8 b0 = *(const bf16x8*)(aBk[ks] + (P) * 32768);                     \
      bf16x8 b1 = *(const bf16x8*)(aBk[ks] + (P) * 32768 + 4096);              \
      bf16x8 a0 = *(const bf16x8*)(aAk[ks] + (P) * 32768);                     \
      bf16x8 a1 = *(const bf16x8*)(aAk[ks] + (P) * 32768 + 4096);              \
      bf16x8 a2 = *(const bf16x8*)(aAk[ks] + (P) * 32768 + 8192);              \
      bf16x8 a3 = *(const bf16x8*)(aAk[ks] + (P) * 32768 + 12288);             \
      __builtin_amdgcn_s_setprio(1);                                           \
      acc[0][0] = __builtin_amdgcn_mfma_f32_32x32x16_bf16(a0, b0, acc[0][0], 0, 0, 0); \
      acc[0][1] = __builtin_amdgcn_mfma_f32_32x32x16_bf16(a0, b1, acc[0][1], 0, 0, 0); \
      acc[1][0] = __builtin_amdgcn_mfma_f32_32x32x16_bf16(a1, b0, acc[1][0], 0, 0, 0); \
      acc[1][1] = __builtin_amdgcn_mfma_f32_32x32x16_bf16(a1, b1, acc[1][1], 0, 0, 0); \
      acc[2][0] = __builtin_amdgcn_mfma_f32_32x32x16_bf16(a2, b0, acc[2][0], 0, 0, 0); \
      acc[2][1] = __builtin_amdgcn_mfma_f32_32x32x16_bf16(a2, b1, acc[2][1], 0, 0, 0); \
      acc[3][0] = __builtin_amdgcn_mfma_f32_32x32x16_bf16(a3, b0, acc[3][0], 0, 0, 0); \
      acc[3][1] = __builtin_amdgcn_mfma_f32_32x32x16_bf16(a3, b1, acc[3][1], 0, 0, 0); \
      __builtin_amdgcn_s_setprio(0);                                           \
    }                                                                          \
    __builtin_amdgcn_s_barrier();                                              \
    if ((T) + 2 < nt) STA(P);                                                  \
    if ((T) + 1 < nt) {                                                        \
      if ((T) + 2 < nt) asm volatile("s_waitcnt vmcnt(4)" ::: "memory");       \
      else              asm volatile("s_waitcnt vmcnt(0)" ::: "memory");       \
      __builtin_amdgcn_s_barrier();                                            \
    }                                                                          \
  }

  for (int t = 0; t < nt; t += 2) {
    GTILE(0, t);
    GTILE(1, t + 1);
  }
#undef GTILE

#pragma unroll
  for (int mr = 0; mr < 4; ++mr) {
#pragma unroll
    for (int nr = 0; nr < 2; ++nr) {
      const int col = n0 + wn * 64 + nr * 32 + l31;
      const float bval = bias[col];
#pragma unroll
      for (int reg = 0; reg < 16; ++reg) {
        const int row = m0 + wm * 128 + mr * 32 + (reg & 3) + 8 * (reg >> 2) + 4 * hi5;
        const float v = acc[mr][nr][reg] + bval;
        const size_t oi = (size_t)row * N + col;
        if constexpr (MODE == 2) {
          ((unsigned short*)out)[oi] = f2bf(gelu_tanh(v));
        } else {
          ((unsigned short*)out)[oi] = f2bf(v);
        }
      }
    }
  }
}

// ---------------- 256x128 counted-vmcnt GEMM (32x32x16, fp32 out + res) -----
// 8 waves (4M x 2N); wave = 64M x 64N = 2 mrep x 2 nrep of 32x32.
__global__ __launch_bounds__(512, 2) void gemm8pn_kernel(
    const unsigned short* __restrict__ A, const unsigned short* __restrict__ BT,
    const float* __restrict__ bias, const float* __restrict__ res,
    float* __restrict__ out, int N, int Kstride, int Klen) {
  __shared__ __align__(16) unsigned short SA[2][2][8192];  // 64KB
  __shared__ __align__(16) unsigned short SB[2][8192];     // 32KB
  const int nwg = gridDim.x * gridDim.y;
  int d = blockIdx.y * gridDim.x + blockIdx.x;
  d = (d & 7) * (nwg >> 3) + (d >> 3);
  const int n0 = (d % gridDim.x) * 128, m0 = (d / gridDim.x) * 256;

  const int tid = threadIdx.x, wv = tid >> 6, ln = tid & 63;
  const int wm = wv >> 1, wn = wv & 1;       // 4M x 2N
  const int l31 = ln & 31, hi5 = ln >> 5;

  const unsigned short* Abase = A + (size_t)m0 * Kstride;
  const unsigned short* Bbase = BT + (size_t)n0 * Kstride;

  const int srow = ln >> 3;
  const int skg = (ln & 7) ^ srow;
  const unsigned short* ga00 = Abase + (size_t)((0 * 8 + wv) * 8 + srow) * Kstride + skg * 8;
  const unsigned short* ga01 = Abase + (size_t)((1 * 8 + wv) * 8 + srow) * Kstride + skg * 8;
  const unsigned short* ga10 = Abase + (size_t)(128 + (0 * 8 + wv) * 8 + srow) * Kstride + skg * 8;
  const unsigned short* ga11 = Abase + (size_t)(128 + (1 * 8 + wv) * 8 + srow) * Kstride + skg * 8;
  const unsigned short* gb0 = Bbase + (size_t)((0 * 8 + wv) * 8 + srow) * Kstride + skg * 8;
  const unsigned short* gb1 = Bbase + (size_t)((1 * 8 + wv) * 8 + srow) * Kstride + skg * 8;

  auto STA = [&](int pbuf) {
    gload_lds16(ga00, (char*)SA + pbuf * 32768 + wv * 1024);
    gload_lds16(ga01, (char*)SA + pbuf * 32768 + (8 + wv) * 1024);
    gload_lds16(ga10, (char*)SA + pbuf * 32768 + 16384 + wv * 1024);
    gload_lds16(ga11, (char*)SA + pbuf * 32768 + 16384 + (8 + wv) * 1024);
    ga00 += 64; ga01 += 64; ga10 += 64; ga11 += 64;
  };
  auto STB = [&](int pbuf) {
    gload_lds16(gb0, (char*)SB + pbuf * 16384 + wv * 1024);
    gload_lds16(gb1, (char*)SB + pbuf * 16384 + (8 + wv) * 1024);
    gb0 += 64; gb1 += 64;
  };

  const int x7 = l31 & 7;
  const char* aAk[4];
  const char* aBk[4];
#pragma unroll
  for (int ks = 0; ks < 4; ++ks) {
    const int ko = ((ks * 2 + hi5) ^ x7) * 16;
    aAk[ks] = (const char*)SA + (wm >> 1) * 16384 + (wm & 1) * 8192 + l31 * 128 + ko;
    aBk[ks] = (const char*)SB + wn * 8192 + l31 * 128 + ko;
  }

  f32x16 acc[2][2] = {};
  const int nt = Klen >> 6;

  STA(0);
  STB(0);
  STA(1);
  asm volatile("s_waitcnt vmcnt(4)" ::: "memory");
  __builtin_amdgcn_s_barrier();

#define GTILEN(P, T)                                                           \
  {                                                                            \
    if ((T) + 1 < nt) STB((P) ^ 1);                                            \
    _Pragma("unroll")                                                          \
    for (int ks = 0; ks < 4; ++ks) {                                           \
      bf16x8 b0 = *(const bf16x8*)(aBk[ks] + (P) * 16384);                     \
      bf16x8 b1 = *(const bf16x8*)(aBk[ks] + (P) * 16384 + 4096);              \
      bf16x8 a0 = *(const bf16x8*)(aAk[ks] + (P) * 32768);                     \
      bf16x8 a1 = *(const bf16x8*)(aAk[ks] + (P) * 32768 + 4096);              \
      __builtin_amdgcn_s_setprio(1);                                           \
      acc[0][0] = __builtin_amdgcn_mfma_f32_32x32x16_bf16(a0, b0, acc[0][0], 0, 0, 0); \
      acc[0][1] = __builtin_amdgcn_mfma_f32_32x32x16_bf16(a0, b1, acc[0][1], 0, 0, 0); \
      acc[1][0] = __builtin_amdgcn_mfma_f32_32x32x16_bf16(a1, b0, acc[1][0], 0, 0, 0); \
      acc[1][1] = __builtin_amdgcn_mfma_f32_32x32x16_bf16(a1, b1, acc[1][1], 0, 0, 0); \
      __builtin_amdgcn_s_setprio(0);                                           \
    }                                                                          \
    __builtin_amdgcn_s_barrier();                                              \
    if ((T) + 2 < nt) STA(P);                                                  \
    if ((T) + 1 < nt) {                                                        \
      if ((T) + 2 < nt) asm volatile("s_waitcnt vmcnt(4)" ::: "memory");       \
      else              asm volatile("s_waitcnt vmcnt(0)" ::: "memory");       \
      __builtin_amdgcn_s_barrier();                                            \
    }                                                                          \
  }

  for (int t = 0; t < nt; t += 2) {
    GTILEN(0, t);
    GTILEN(1, t + 1);
  }
#undef GTILEN

#pragma unroll
  for (int mr = 0; mr < 2; ++mr) {
#pragma unroll
    for (int nr = 0; nr < 2; ++nr) {
      const int col = n0 + wn * 64 + nr * 32 + l31;
      const float bval = bias[col];
#pragma unroll
      for (int reg = 0; reg < 16; ++reg) {
        const int row = m0 + wm * 64 + mr * 32 + (reg & 3) + 8 * (reg >> 2) + 4 * hi5;
        const size_t oi = (size_t)row * N + col;
        out[oi] = acc[mr][nr][reg] + bval + res[oi];
      }
    }
  }
}

// -------------------------- LoRA2 + theta (clip) ----------------------------
__global__ __launch_bounds__(256) void lora2_kernel(
    const unsigned short* __restrict__ qkv, const float* __restrict__ w2,
    const float* __restrict__ tbase, float* __restrict__ theta) {
  __shared__ float lt[8][48];
  const int m0 = blockIdx.x * 32;
  const int tid = threadIdx.x;
  const int col = tid * 2;
  const float tb0 = tbase[col], tb1 = tbase[col + 1];
  for (int grp = 0; grp < 4; ++grp) {
    const int mg = m0 + grp * 8;
    __syncthreads();
    for (int idx = tid; idx < 384; idx += 256) {
      const int tok = idx / 48, jj = idx % 48;
      lt[tok][jj] = tanhf(bf2f(qkv[(size_t)(mg + tok) * QS + 3072 + jj]));
    }
    __syncthreads();
    float a0[8], a1[8];
#pragma unroll
    for (int tok = 0; tok < 8; ++tok) { a0[tok] = tb0; a1[tok] = tb1; }
    for (int jj = 0; jj < 48; ++jj) {
      const float2 w = *(const float2*)&w2[(size_t)jj * 512 + col];
#pragma unroll
      for (int tok = 0; tok < 8; ++tok) {
        const float l = lt[tok][jj];
        a0[tok] = fmaf(l, w.x, a0[tok]);
        a1[tok] = fmaf(l, w.y, a1[tok]);
      }
    }
    const float CL = 1.5707963267948966f;
#pragma unroll
    for (int tok = 0; tok < 8; ++tok) {
      float c0 = fminf(fmaxf(a0[tok], -CL), CL);
      float c1 = fminf(fmaxf(a1[tok], -CL), CL);
      *(float2*)&theta[(size_t)(mg + tok) * 512 + col] = make_float2(c0, c1);
    }
  }
}

// ------------------------------- attn_intra ---------------------------------
__global__ __launch_bounds__(256) void attn_intra(
    const unsigned short* __restrict__ qkv, const float* __restrict__ theta,
    const float* __restrict__ lamb, const float* __restrict__ eta,
    float* __restrict__ yi, unsigned short* __restrict__ QG,
    unsigned short* __restrict__ TCG, float* __restrict__ Dg) {
  const int c = blockIdx.x, bh = blockIdx.y;
  const int b = bh >> 4, h = bh & 15;
  const int tid = threadIdx.x, wv = tid >> 6, lane = tid & 63;
  const int sc = c * 4 + wv;
  const int cid = bh * 128 + sc;
  const int mw = b * 2048 + sc * 16;

  __shared__ unsigned short QDm[4][16][64];
  __shared__ unsigned short KDm[4][16][64];
  __shared__ unsigned short KdET[4][64][32];
  __shared__ unsigned short VT[4][64][32];
  __shared__ unsigned short Gs[4][16][32];

  {
    unsigned int* kz = (unsigned int*)&KdET[wv][0][0];
    unsigned int* vz = (unsigned int*)&VT[wv][0][0];
    for (int idx = lane; idx < 512; idx += 64) {
      const int r = idx >> 3, p = (idx & 7) + 8;
      kz[r * 16 + p] = 0; vz[r * 16 + p] = 0;
    }
    unsigned int* gz = (unsigned int*)&Gs[wv][0][0];
    for (int idx = lane; idx < 128; idx += 64) {
      const int r = idx >> 3, p = (idx & 7) + 8;
      gz[r * 16 + p] = 0;
    }
  }
  for (int ss = 0; ss < 16; ++ss)
    VT[wv][lane][ss] = qkv[(size_t)(mw + ss) * QS + 2048 + h * 64 + lane];

  const int bk = lane & 31, th = lane >> 5;
  const float lb = lamb[h * 32 + bk], et = eta[h * 32 + bk];
  float L[8], Th[8], qr[8], qi[8], kr[8], ki[8];
  float runL = 0.f, runT = 0.f;
#pragma unroll
  for (int i = 0; i < 8; ++i) {
    const size_t m = (size_t)(mw + th * 8 + i);
    const float tv = theta[m * 512 + h * 32 + bk];
    const float lam = fmaf(et * tv, tv, lb);
    runL += lam; L[i] = runL;
    runT += tv;  Th[i] = runT;
    const unsigned int qp = *(const unsigned int*)&qkv[m * QS + h * 64 + 2 * bk];
    const unsigned int kp = *(const unsigned int*)&qkv[m * QS + 1024 + h * 64 + 2 * bk];
    qr[i] = bf2f((unsigned short)(qp & 0xFFFF)); qi[i] = bf2f((unsigned short)(qp >> 16));
    const float kx = bf2f((unsigned short)(kp & 0xFFFF));
    const float ky = bf2f((unsigned short)(kp >> 16));
    kr[i] = kx > 0.f ? kx + 1.f : __expf(kx);
    ki[i] = ky > 0.f ? ky + 1.f : __expf(ky);
  }
  const float oL = __shfl_xor(runL, 32), oT = __shfl_xor(runT, 32);
  const float Lm = th ? oL : runL;
  const float Tm = th ? oT : runT;
  const float Ltot = runL + oL, Ttot = runT + oT;
  const float Lbase = th ? oL : 0.f, Tbase = th ? oT : 0.f;
  float Es, Ec; __sincosf(Tm, &Es, &Ec);
  const float Ee = __expf(-Lm);
  const float Er = Ee * Ec, Ei = Ee * Es;
  float Fs, Fc; __sincosf(Ttot - Tm, &Fs, &Fc);
  const float Fe = __expf(-(Ltot - Lm));
  const float Fr = Fe * Fc, Fi = Fe * Fs;
  if (th == 0) {
    float Ds, Dc; __sincosf(Ttot, &Ds, &Dc);
    const float De = __expf(-Ltot);
    *(float2*)&Dg[((size_t)cid * 32 + bk) * 2] = make_float2(De * Dc, De * Ds);
  }
  unsigned int* qd32 = (unsigned int*)&QDm[wv][0][0];
  unsigned int* kd32 = (unsigned int*)&KDm[wv][0][0];
#pragma unroll
  for (int i = 0; i < 8; ++i) {
    const int t = th * 8 + i;
    const float Lg = Lbase + L[i], Tg = Tbase + Th[i];
    const float dm = __expf(-(Lg - Lm));
    float sn, cs; __sincosf(Tg - Tm, &sn, &cs);
    const float qmr = dm * (qr[i] * cs + qi[i] * sn);
    const float qmi = dm * (qr[i] * sn - qi[i] * cs);
    const float rd = 1.f / dm;
    const float kmr = rd * (kr[i] * cs + ki[i] * sn);
    const float kmi = rd * (ki[i] * cs - kr[i] * sn);
    const int sidx = (t * 32 + bk) ^ ((t & 7) << 2);
    qd32[sidx] = pack2(qmr, qmi);
    kd32[sidx] = pack2(kmr, -kmi);
    ((unsigned int*)QG)[(size_t)cid * 512 + t * 32 + bk] =
        pack2(qmr * Er - qmi * Ei, qmr * Ei + qmi * Er);
    const float er = kmr * Fr - kmi * Fi;
    const float ei = kmr * Fi + kmi * Fr;
    KdET[wv][bk][t] = f2bf(er);
    KdET[wv][32 + bk][t] = f2bf(ei);
  }

  const int l15 = lane & 15, hi = lane >> 4;
  const char* qb = (const char*)&QDm[wv][0][0];
  const char* kb = (const char*)&KDm[wv][0][0];
  f32x4 z = {};
  f32x4 g = z;
  {
    bf16x8 a0 = *(const bf16x8*)(qb + l15 * 128 + ((16 * hi) ^ ((l15 & 7) << 4)));
    bf16x8 b0 = *(const bf16x8*)(kb + l15 * 128 + ((16 * hi) ^ ((l15 & 7) << 4)));
    bf16x8 a1 = *(const bf16x8*)(qb + l15 * 128 + ((64 + 16 * hi) ^ ((l15 & 7) << 4)));
    bf16x8 b1 = *(const bf16x8*)(kb + l15 * 128 + ((64 + 16 * hi) ^ ((l15 & 7) << 4)));
    g = __builtin_amdgcn_mfma_f32_16x16x32_bf16(a0, b0, g, 0, 0, 0);
    g = __builtin_amdgcn_mfma_f32_16x16x32_bf16(a1, b1, g, 0, 0, 0);
  }
#pragma unroll
  for (int r = 0; r < 4; ++r) {
    const float gv = (l15 <= 4 * hi + r) ? g[r] : 0.f;
    Gs[wv][4 * hi + r][l15] = f2bf(gv);
  }
  const char* gsb = (const char*)&Gs[wv][0][0];
  const char* vtb = (const char*)&VT[wv][0][0];
  bf16x8 aG = *(const bf16x8*)(gsb + l15 * 64 + 16 * hi);
#pragma unroll
  for (int nt = 0; nt < 4; ++nt) {
    bf16x8 bV = *(const bf16x8*)(vtb + (nt * 16 + l15) * 64 + 16 * hi);
    f32x4 y = __builtin_amdgcn_mfma_f32_16x16x32_bf16(aG, bV, z, 0, 0, 0);
#pragma unroll
    for (int r = 0; r < 4; ++r)
      yi[(size_t)cid * 1024 + (4 * hi + r) * 64 + nt * 16 + l15] = y[r];
  }
  const char* keb = (const char*)&KdET[wv][0][0];
#pragma unroll
  for (int mt = 0; mt < 4; ++mt) {
    bf16x8 aT = *(const bf16x8*)(keb + (mt * 16 + l15) * 64 + 16 * hi);
#pragma unroll
    for (int nt = 0; nt < 4; ++nt) {
      bf16x8 bV = *(const bf16x8*)(vtb + (nt * 16 + l15) * 64 + 16 * hi);
      f32x4 t4 = __builtin_amdgcn_mfma_f32_16x16x32_bf16(aT, bV, z, 0, 0, 0);
#pragma unroll
      for (int r = 0; r < 4; ++r)
        TCG[(size_t)cid * 4096 + (mt * 16 + 4 * hi + r) * 64 + nt * 16 + l15] = f2bf(t4[r]);
    }
  }
}

// ------------------------------- scanB (coalesced) --------------------------
__global__ __launch_bounds__(256) void scanB_kernel(
    const unsigned short* __restrict__ TCG, const float* __restrict__ Dg,
    unsigned int* __restrict__ CPACK) {
  const int bh = blockIdx.x & 63, g = blockIdx.x >> 6;
  const int tid = threadIdx.x;
  const int v = tid & 63, bk = g * 4 + (tid >> 6);
  const size_t base = (size_t)bh * 128;
  float Cr = 0.f, Ci = 0.f;
  float trx[4], tix[4]; float2 dx[4];
  auto LOADQ = [&](int c0, float* tr, float* ti, float2* dd) {
#pragma unroll
    for (int u = 0; u < 4; ++u) {
      const size_t cid = base + c0 + u;
      tr[u] = bf2f(TCG[cid * 4096 + bk * 64 + v]);
      ti[u] = bf2f(TCG[cid * 4096 + (32 + bk) * 64 + v]);
      dd[u] = *(const float2*)&Dg[(cid * 32 + bk) * 2];
    }
  };
  LOADQ(0, trx, tix, dx);
  for (int c0 = 0; c0 < 128; c0 += 4) {
    float tra[4], tia[4]; float2 da[4];
#pragma unroll
    for (int u = 0; u < 4; ++u) { tra[u] = trx[u]; tia[u] = tix[u]; da[u] = dx[u]; }
    if (c0 + 4 < 128) LOADQ(c0 + 4, trx, tix, dx);
#pragma unroll
    for (int u = 0; u < 4; ++u) {
      CPACK[(base + c0 + u) * 2048 + bk * 64 + v] = pack2(Cr, -Ci);
      const float nr = fmaf(da[u].x, Cr, fmaf(-da[u].y, Ci, tra[u]));
      const float ni = fmaf(da[u].x, Ci, fmaf(da[u].y, Cr, tia[u]));
      Cr = nr; Ci = ni;
    }
  }
}

// ------------------------------- attn_cross ---------------------------------
__global__ __launch_bounds__(256) void attn_cross(
    const float* __restrict__ yi, const unsigned short* __restrict__ QG,
    const unsigned int* __restrict__ CPACK, unsigned short* __restrict__ attn) {
  const int c = blockIdx.x, bh = blockIdx.y;
  const int b = bh >> 4, h = bh & 15;
  const int tid = threadIdx.x, wv = tid >> 6, lane = tid & 63;
  const int sc = c * 4 + wv, cid = bh * 128 + sc;
  const int mw = b * 2048 + sc * 16;
  __shared__ unsigned short Cp[4][64][64];
  __shared__ unsigned short Qs[4][16][64];
  unsigned int* cp32 = (unsigned int*)&Cp[wv][0][0];
  const unsigned int* cg = CPACK + (size_t)cid * 2048;
  for (int bkq = 0; bkq < 32; ++bkq) {
    cp32[(lane * 32 + bkq) ^ ((lane & 7) << 2)] = cg[bkq * 64 + lane];
  }
  unsigned int* qs32 = (unsigned int*)&Qs[wv][0][0];
  const unsigned int* qg = (const unsigned int*)QG + (size_t)cid * 512;
  for (int ii = 0; ii < 8; ++ii) {
    const int flat = ii * 64 + lane;
    const int row = flat >> 5, col = flat & 31;
    qs32[(row * 32 + col) ^ ((row & 7) << 2)] = qg[flat];
  }
  const int l15 = lane & 15, hi = lane >> 4;
  const char* qb = (const char*)&Qs[wv][0][0];
  const char* cb = (const char*)&Cp[wv][0][0];
  bf16x8 a0 = *(const bf16x8*)(qb + l15 * 128 + ((16 * hi) ^ ((l15 & 7) << 4)));
  bf16x8 a1 = *(const bf16x8*)(qb + l15 * 128 + ((64 + 16 * hi) ^ ((l15 & 7) << 4)));
  f32x4 z = {};
#pragma unroll
  for (int nt = 0; nt < 4; ++nt) {
    const int vr = nt * 16 + l15;
    bf16x8 b0 = *(const bf16x8*)(cb + vr * 128 + ((16 * hi) ^ ((vr & 7) << 4)));
    bf16x8 b1 = *(const bf16x8*)(cb + vr * 128 + ((64 + 16 * hi) ^ ((vr & 7) << 4)));
    f32x4 y = __builtin_amdgcn_mfma_f32_16x16x32_bf16(a0, b0, z, 0, 0, 0);
    y = __builtin_amdgcn_mfma_f32_16x16x32_bf16(a1, b1, y, 0, 0, 0);
#pragma unroll
    for (int r = 0; r < 4; ++r) {
      const int t = 4 * hi + r;
      const float out = y[r] + yi[(size_t)cid * 1024 + t * 64 + vr];
      attn[(size_t)(mw + t) * 1024 + h * 64 + vr] = f2bf(out);
    }
  }
}

// ---------------------------------------------------------------------------
extern "C" void kernel_launch(void* const* d_in, const int* in_sizes, int n_in,
                              void* d_out, int out_size, void* d_ws, size_t ws_size,
                              hipStream_t stream) {
  const float* x   = (const float*)d_in[0];
  const float* Wq  = (const float*)d_in[1];
  const float* bq  = (const float*)d_in[2];
  const float* Wk  = (const float*)d_in[3];
  const float* bk_ = (const float*)d_in[4];
  const float* Wv  = (const float*)d_in[5];
  const float* bv  = (const float*)d_in[6];
  const float* Wo  = (const float*)d_in[7];
  const float* bo  = (const float*)d_in[8];
  const float* n1g = (const float*)d_in[9];
  const float* n1b = (const float*)d_in[10];
  const float* n2g = (const float*)d_in[11];
  const float* n2b = (const float*)d_in[12];
  const float* thb = (const float*)d_in[13];
  const float* tw1 = (const float*)d_in[14];
  const float* tw2 = (const float*)d_in[15];
  const float* lamb= (const float*)d_in[16];
  const float* eta = (const float*)d_in[17];
  const float* Wf1 = (const float*)d_in[18];
  const float* bf1 = (const float*)d_in[19];
  const float* Wf2 = (const float*)d_in[20];
  const float* bf2 = (const float*)d_in[21];

  char* ws = (char*)d_ws;
  size_t off = 0;
  auto alloc = [&](size_t bytes) {
    size_t r = off;
    off += (bytes + 255) & ~(size_t)255;
    return r;
  };
  unsigned short* WCAT = (unsigned short*)(ws + alloc((size_t)QS * 1024 * 2));
  unsigned short* WOT  = (unsigned short*)(ws + alloc(1024ull * 1024 * 2));
  unsigned short* WF1T = (unsigned short*)(ws + alloc(4096ull * 1024 * 2));
  unsigned short* WF2T = (unsigned short*)(ws + alloc(1024ull * 4096 * 2));
  float* BIASC = (float*)(ws + alloc((size_t)QS * 4));
  unsigned short* XN = (unsigned short*)(ws + alloc(8192ull * 1024 * 2));  // also LN2 out
  char* QKVbase = ws + alloc(8192ull * 4096 * 2);   // QKV bf16(QS) / CPACK / GBUF
  unsigned short* QKV = (unsigned short*)QKVbase;
  unsigned int* CPACK = (unsigned int*)QKVbase;     // after attn_intra
  unsigned short* GBUF = (unsigned short*)QKVbase;  // after attn_cross
  float* THETA = (float*)(ws + alloc(8192ull * 512 * 4));   // also ATTN bf16
  unsigned short* ATTN = (unsigned short*)THETA;
  float* YI = (float*)(ws + alloc(8192ull * 1024 * 4));     // also X1
  float* X1 = YI;
  unsigned short* QG = (unsigned short*)(ws + alloc(8192ull * 1024 * 2));
  unsigned short* TCG = (unsigned short*)(ws + alloc(8192ull * 4096 * 2)); // T (read-only after intra)
  float* DG = (float*)(ws + alloc(8192ull * 32 * 2 * 4));

  if (ws_size < off) {
    fill_kernel<<<dim3((out_size + 255) / 256), dim3(256), 0, stream>>>((float*)d_out, 12345.0f, out_size);
    return;
  }

  const dim3 b256(256), b512(512);

  // unified weight prep (1 launch)
  prep_all<<<dim3(12557), b256, 0, stream>>>(Wq, Wk, Wv, tw1, Wo, Wf1, Wf2,
                                             bq, bk_, bv, WCAT, WOT, WF1T, WF2T, BIASC);

  // LN1 -> xn (bf16)
  ln_kernel<<<dim3(8192), b256, 0, stream>>>(x, n1g, n1b, XN);
  // QKV + lora1 (bf16 out, stride QS) — 256^2 counted-vmcnt (32x32)
  gemm8p_kernel<3><<<dim3(13, 32), b512, 0, stream>>>(XN, WCAT, BIASC, QKV, QS, 1024, 1024);
  // lora2 -> theta
  lora2_kernel<<<dim3(256), b256, 0, stream>>>(QKV, tw2, thb, THETA);
  // attention
  attn_intra<<<dim3(32, 64), b256, 0, stream>>>(QKV, THETA, lamb, eta, YI, QG, TCG, DG);
  scanB_kernel<<<dim3(512), b256, 0, stream>>>(TCG, DG, CPACK);
  attn_cross<<<dim3(32, 64), b256, 0, stream>>>(YI, QG, CPACK, ATTN);
  // x1 = x + attn@Wo + bo — 256x128 counted-vmcnt (32x32, fp32 + res)
  gemm8pn_kernel<<<dim3(8, 32), b512, 0, stream>>>(ATTN, WOT, bo, x, X1, 1024, 1024, 1024);
  // LN2
  ln_kernel<<<dim3(8192), b256, 0, stream>>>(X1, n2g, n2b, XN);
  // FFN1 (gelu, bf16 out) — 256^2 counted-vmcnt (32x32)
  gemm8p_kernel<2><<<dim3(16, 32), b512, 0, stream>>>(XN, WF1T, bf1, GBUF, 4096, 1024, 1024);
  // FFN2 — 256x128 counted-vmcnt (32x32), full K, fp32 + res -> d_out
  gemm8pn_kernel<<<dim3(8, 32), b512, 0, stream>>>(GBUF, WF2T, bf2, X1, (float*)d_out, 1024, 4096, 4096);
}